// Round 18
// baseline (134.000 us; speedup 1.0000x reference)
//
#include <hip/hip_runtime.h>

#define NB 32
#define NN 2048
#define ND 128
#define NSUP 2032
#define KKEEP 1016
#define MM 1032
#define SEG 254              // NSUP / 8 segments per batch

typedef unsigned long long u64;
typedef unsigned int u32;
typedef float f32x4 __attribute__((ext_vector_type(4)));   // clang-native vec4

// Opaque IEEE f32 RN ops — compiler cannot contract/reassociate these.
__device__ __forceinline__ float mulrn(float a, float b) {
  float r;
  asm("v_mul_f32 %0, %1, %2" : "=v"(r) : "v"(a), "v"(b));
  return r;
}
__device__ __forceinline__ float addrn(float a, float b) {
  float r;
  asm("v_add_f32 %0, %1, %2" : "=v"(r) : "v"(a), "v"(b));
  return r;
}
// Single-rounded FMA — matches x86 vfmadd exactly.
__device__ __forceinline__ float fmarn(float a, float b, float c) {
  float r;
  asm("v_fma_f32 %0, %1, %2, %3" : "=v"(r) : "v"(a), "v"(b), "v"(c));
  return r;
}

// ---------------------------------------------------------------------------
// K1: bit-exact JAX/XLA-CPU f32 score (VERIFIED round 10 — do not change).
// ---------------------------------------------------------------------------
__global__ __launch_bounds__(256) void k_score(const float* __restrict__ X,
                                               const float* __restrict__ w,
                                               const float* __restrict__ bias,
                                               u64* __restrict__ keys,
                                               float* __restrict__ score) {
#pragma clang fp contract(off)
  int row = blockIdx.x * 256 + threadIdx.x;
  if (row >= NB * NN) return;
  const float* x = X + (size_t)row * ND;

  float l[16];
  #pragma unroll
  for (int k = 0; k < 16; ++k) l[k] = 0.f;
  #pragma unroll
  for (int step = 0; step < 8; ++step) {
    const float* xp = x + step * 16;
    const float* wp = w + step * 16;
    #pragma unroll
    for (int q4 = 0; q4 < 4; ++q4) {
      const float4 xv = *reinterpret_cast<const float4*>(xp + q4 * 4);
      const float4 wv = *reinterpret_cast<const float4*>(wp + q4 * 4);
      l[q4 * 4 + 0] = addrn(mulrn(xv.x, wv.x), l[q4 * 4 + 0]);
      l[q4 * 4 + 1] = addrn(mulrn(xv.y, wv.y), l[q4 * 4 + 1]);
      l[q4 * 4 + 2] = addrn(mulrn(xv.z, wv.z), l[q4 * 4 + 2]);
      l[q4 * 4 + 3] = addrn(mulrn(xv.w, wv.w), l[q4 * 4 + 3]);
    }
  }
  #pragma unroll
  for (int k = 0; k < 8; ++k) l[k] = addrn(l[k], l[k + 8]);
  #pragma unroll
  for (int k = 0; k < 4; ++k) l[k] = addrn(l[k], l[k + 4]);
  l[0] = addrn(l[0], l[2]);
  l[1] = addrn(l[1], l[3]);
  const float dot = addrn(l[0], l[1]);

  const float z = __fdiv_rn(addrn(dot, bias[0]), 100.0f);

  const float xe = -z;
  const float z2 = mulrn(xe, xe);
  float y = fmarn(1.9875691500E-4f, xe, 1.3981999507E-3f);
  y = fmarn(y, xe, 8.3334519073E-3f);
  y = fmarn(y, xe, 4.1665795894E-2f);
  y = fmarn(y, xe, 1.6666665459E-1f);
  y = fmarn(y, xe, 5.0000001201E-1f);
  y = fmarn(y, z2, xe);
  const float e = addrn(y, 1.0f);

  const float s = __fdiv_rn(1.0f, addrn(1.0f, e));

  score[row] = s;

  const u32 sb = __float_as_uint(s);   // s>0 -> bits ascending-sortable
  const int n = row & (NN - 1);
  keys[row] = ((u64)sb << 32) | (u32)n;
}

// ---------------------------------------------------------------------------
// K2 v5: rank-by-counting with a SCALAR key stream (no LDS). The inner
//   address keys[bNN+s] is wave-uniform -> s_load_dwordx16 through the
//   scalar K$ (reused by all 4 waves); compare is v_cmp vs SGPR pair.
//   Moves the scan off the per-CU LDS pipe onto the 4 parallel SIMDs.
//   Selection semantics identical: rank == output position, rank<1016 kept.
// ---------------------------------------------------------------------------
__global__ __launch_bounds__(256) void k_rank(const u64* __restrict__ keys,
                                              const float* __restrict__ score,
                                              int* __restrict__ idxs,
                                              float* __restrict__ vals,
                                              float* __restrict__ out_idx) {
  const int b   = blockIdx.x >> 3;
  const int seg = blockIdx.x & 7;
  const int t   = threadIdx.x;
  const size_t bNN = (size_t)b * NN;
  const int    bMM = b * MM;
  const u64* kb = keys + bNN;

  if (t < SEG) {
    const int e  = seg * SEG + t;
    const u64 my = kb[e];
    int cnt = 0;
    for (int s = 0; s < NSUP; s += 8) {      // NSUP % 8 == 0
      const u64 k0 = kb[s + 0], k1 = kb[s + 1], k2 = kb[s + 2], k3 = kb[s + 3];
      const u64 k4 = kb[s + 4], k5 = kb[s + 5], k6 = kb[s + 6], k7 = kb[s + 7];
      cnt += (int)(k0 < my) + (int)(k1 < my) + (int)(k2 < my) + (int)(k3 < my)
           + (int)(k4 < my) + (int)(k5 < my) + (int)(k6 < my) + (int)(k7 < my);
    }
    if (cnt < KKEEP) {
      idxs[bMM + cnt]    = e;
      vals[bMM + cnt]    = score[bNN + e];
      out_idx[bMM + cnt] = (float)e;
    }
  } else if (t < SEG + 2) {
    const int q   = seg * 2 + (t - SEG);     // 0..15
    const int e   = NSUP + q;
    const int pos = KKEEP + q;
    idxs[bMM + pos]    = e;
    vals[bMM + pos]    = score[bNN + e];
    out_idx[bMM + pos] = (float)e;
  }
}

// ---------------------------------------------------------------------------
// K4 v6: R14 structure minus the scols LDS buffer. One 128-thread block per
//   output row; A-row staged through LDS (8 KB -> 16 blocks/CU, wave-limited
//   max, +23% in-flight reads vs 13); column indices read as int4 from
//   global (4 KB/batch shared by 1032 blocks -> L2-resident).
//   Nontemporal A loads / new_A stores. Fused new_X on lanes 0-31.
// ---------------------------------------------------------------------------
__global__ __launch_bounds__(128) void k_newa(const float* __restrict__ A,
                                              const float* __restrict__ X,
                                              const int* __restrict__ idxs,
                                              const float* __restrict__ vals,
                                              float* __restrict__ out_a,
                                              float* __restrict__ out_x) {
  __shared__ float srow[NN];     // 8 KiB
  const int t   = threadIdx.x;
  const int row = blockIdx.x;           // 0 .. NB*MM-1
  const int b   = row / MM;
  const int4* cols4 = reinterpret_cast<const int4*>(idxs + b * MM);

  const int ri = idxs[row];             // uniform per block
  const float* arow = A + ((size_t)b * NN + ri) * NN;
  #pragma unroll
  for (int i = 0; i < 4; ++i) {         // 2048 floats = 512 f32x4
    const int off = (t + i * 128) * 4;
    *reinterpret_cast<f32x4*>(&srow[off]) =
        __builtin_nontemporal_load(reinterpret_cast<const f32x4*>(arow + off));
  }

  if (t < 32) {                         // fused new_X
    const float v = vals[row];
    const float4 xv = reinterpret_cast<const float4*>(
        X + ((size_t)b * NN + ri) * ND)[t];
    float4 o = make_float4(xv.x * v, xv.y * v, xv.z * v, xv.w * v);
    reinterpret_cast<float4*>(out_x + (size_t)row * ND)[t] = o;
  }
  __syncthreads();

  f32x4* orow = reinterpret_cast<f32x4*>(out_a + (size_t)row * MM);
  for (int c = t; c < MM / 4; c += 128) {
    const int4 j4 = cols4[c];           // L2-hot
    f32x4 o;
    o.x = srow[j4.x];
    o.y = srow[j4.y];
    o.z = srow[j4.z];
    o.w = srow[j4.w];
    __builtin_nontemporal_store(o, orow + c);
  }
}

extern "C" void kernel_launch(void* const* d_in, const int* in_sizes, int n_in,
                              void* d_out, int out_size, void* d_ws, size_t ws_size,
                              hipStream_t stream) {
  const float* A    = (const float*)d_in[0];   // [32,2048,2048]
  const float* X    = (const float*)d_in[1];   // [32,2048,128]
  const float* w    = (const float*)d_in[2];   // [128]
  const float* bias = (const float*)d_in[3];   // [1]

  float* out0 = (float*)d_out;                          // new_A
  float* out1 = out0 + (size_t)NB * MM * MM;            // new_X
  float* out2 = out1 + (size_t)NB * MM * ND;            // idx (as f32)

  u64*   keys  = (u64*)d_ws;                 // [32][2048] u64
  float* score = (float*)(keys + NB * NN);   // [32][2048] f32
  int*   idxs  = (int*)(score + NB * NN);    // [32][1032] i32
  float* vals  = (float*)(idxs + NB * MM);   // [32][1032] f32

  hipLaunchKernelGGL(k_score, dim3(NB * NN / 256), dim3(256), 0, stream, X, w, bias, keys, score);
  hipLaunchKernelGGL(k_rank,  dim3(NB * 8),        dim3(256), 0, stream, keys, score, idxs, vals, out2);
  hipLaunchKernelGGL(k_newa,  dim3(NB * MM),       dim3(128), 0, stream, A, X, idxs, vals, out0, out1);
}

// Round 19
// 110.111 us; speedup vs baseline: 1.2170x; 1.2170x over previous
//
#include <hip/hip_runtime.h>

#define NB 32
#define NN 2048
#define ND 128
#define NSUP 2032
#define KKEEP 1016
#define MM 1032
#define SEG 254              // NSUP / 8 segments per batch

typedef unsigned long long u64;
typedef unsigned int u32;
typedef float f32x4 __attribute__((ext_vector_type(4)));   // clang-native vec4

// Opaque IEEE f32 RN ops — compiler cannot contract/reassociate these.
__device__ __forceinline__ float mulrn(float a, float b) {
  float r;
  asm("v_mul_f32 %0, %1, %2" : "=v"(r) : "v"(a), "v"(b));
  return r;
}
__device__ __forceinline__ float addrn(float a, float b) {
  float r;
  asm("v_add_f32 %0, %1, %2" : "=v"(r) : "v"(a), "v"(b));
  return r;
}
// Single-rounded FMA — matches x86 vfmadd exactly.
__device__ __forceinline__ float fmarn(float a, float b, float c) {
  float r;
  asm("v_fma_f32 %0, %1, %2, %3" : "=v"(r) : "v"(a), "v"(b), "v"(c));
  return r;
}

// ---------------------------------------------------------------------------
// K1: bit-exact JAX/XLA-CPU f32 score (VERIFIED round 10 — do not change):
//   W16 single-accumulator chain with SEPARATE mul/add, halving-tree reduce,
//   CR f32 div by 100, Eigen/Cephes pexp Horner (m=0 regime), 1/(1+e) CR div.
//   KEY = f32 score bits (ref's ulp-ties preserved) | row idx (stable ties).
// ---------------------------------------------------------------------------
__global__ __launch_bounds__(256) void k_score(const float* __restrict__ X,
                                               const float* __restrict__ w,
                                               const float* __restrict__ bias,
                                               u64* __restrict__ keys,
                                               float* __restrict__ score) {
#pragma clang fp contract(off)
  int row = blockIdx.x * 256 + threadIdx.x;
  if (row >= NB * NN) return;
  const float* x = X + (size_t)row * ND;

  float l[16];
  #pragma unroll
  for (int k = 0; k < 16; ++k) l[k] = 0.f;
  #pragma unroll
  for (int step = 0; step < 8; ++step) {
    const float* xp = x + step * 16;
    const float* wp = w + step * 16;
    #pragma unroll
    for (int q4 = 0; q4 < 4; ++q4) {
      const float4 xv = *reinterpret_cast<const float4*>(xp + q4 * 4);
      const float4 wv = *reinterpret_cast<const float4*>(wp + q4 * 4);
      l[q4 * 4 + 0] = addrn(mulrn(xv.x, wv.x), l[q4 * 4 + 0]);
      l[q4 * 4 + 1] = addrn(mulrn(xv.y, wv.y), l[q4 * 4 + 1]);
      l[q4 * 4 + 2] = addrn(mulrn(xv.z, wv.z), l[q4 * 4 + 2]);
      l[q4 * 4 + 3] = addrn(mulrn(xv.w, wv.w), l[q4 * 4 + 3]);
    }
  }
  #pragma unroll
  for (int k = 0; k < 8; ++k) l[k] = addrn(l[k], l[k + 8]);
  #pragma unroll
  for (int k = 0; k < 4; ++k) l[k] = addrn(l[k], l[k + 4]);
  l[0] = addrn(l[0], l[2]);
  l[1] = addrn(l[1], l[3]);
  const float dot = addrn(l[0], l[1]);

  const float z = __fdiv_rn(addrn(dot, bias[0]), 100.0f);

  const float xe = -z;
  const float z2 = mulrn(xe, xe);
  float y = fmarn(1.9875691500E-4f, xe, 1.3981999507E-3f);
  y = fmarn(y, xe, 8.3334519073E-3f);
  y = fmarn(y, xe, 4.1665795894E-2f);
  y = fmarn(y, xe, 1.6666665459E-1f);
  y = fmarn(y, xe, 5.0000001201E-1f);
  y = fmarn(y, z2, xe);
  const float e = addrn(y, 1.0f);

  const float s = __fdiv_rn(1.0f, addrn(1.0f, e));

  score[row] = s;

  const u32 sb = __float_as_uint(s);   // s>0 -> bits ascending-sortable
  const int n = row & (NN - 1);
  keys[row] = ((u64)sb << 32) | (u32)n;
}

// ---------------------------------------------------------------------------
// K2 v3 (VERIFIED round 14): rank-by-counting selection via LDS broadcast
//   scan. rank == output position under (score_bits | idx) ascending;
//   rank < 1016 = selected. 8 blocks/batch; threads SEG..SEG+1 emit queries.
// ---------------------------------------------------------------------------
__global__ __launch_bounds__(256) void k_rank(const u64* __restrict__ keys,
                                              const float* __restrict__ score,
                                              int* __restrict__ idxs,
                                              float* __restrict__ vals,
                                              float* __restrict__ out_idx) {
  __shared__ u64 lk[NSUP];   // 16.3 KiB
  const int b   = blockIdx.x >> 3;
  const int seg = blockIdx.x & 7;
  const int t   = threadIdx.x;
  const size_t bNN = (size_t)b * NN;
  const int    bMM = b * MM;

  for (int i = t; i < NSUP; i += 256) lk[i] = keys[bNN + i];
  __syncthreads();

  if (t < SEG) {
    const int e  = seg * SEG + t;
    const u64 my = lk[e];
    int cnt = 0;
    #pragma unroll 4
    for (int s = 0; s < NSUP; s += 4) {
      const u64 k0 = lk[s], k1 = lk[s + 1], k2 = lk[s + 2], k3 = lk[s + 3];
      cnt += (int)(k0 < my) + (int)(k1 < my) + (int)(k2 < my) + (int)(k3 < my);
    }
    if (cnt < KKEEP) {
      idxs[bMM + cnt]    = e;
      vals[bMM + cnt]    = score[bNN + e];
      out_idx[bMM + cnt] = (float)e;
    }
  } else {
    const int q   = seg * 2 + (t - SEG);   // only t==SEG, SEG+1 matter
    if (t < SEG + 2) {
      const int e   = NSUP + q;
      const int pos = KKEEP + q;
      idxs[bMM + pos]    = e;
      vals[bMM + pos]    = score[bNN + e];
      out_idx[bMM + pos] = (float)e;
    }
  }
}

// ---------------------------------------------------------------------------
// K4 (VERIFIED round 14 best): one 128-thread block per output row
//   (13 blocks/CU). A-row staged through LDS with nontemporal f32x4 loads;
//   scols staged in LDS; gather + nontemporal new_A store; fused new_X on
//   lanes 0-31.
// ---------------------------------------------------------------------------
__global__ __launch_bounds__(128) void k_newa(const float* __restrict__ A,
                                              const float* __restrict__ X,
                                              const int* __restrict__ idxs,
                                              const float* __restrict__ vals,
                                              float* __restrict__ out_a,
                                              float* __restrict__ out_x) {
  __shared__ float srow[NN];     // 8 KiB
  __shared__ int   scols[MM];    // ~4 KiB
  int row = blockIdx.x;                 // 0 .. NB*MM-1
  int b   = row / MM;
  const int* cols = idxs + b * MM;
  for (int c = threadIdx.x; c < MM / 4; c += 128)
    *reinterpret_cast<int4*>(&scols[c * 4]) =
        reinterpret_cast<const int4*>(cols)[c];

  int ri = idxs[row];                   // uniform per block
  const float* arow = A + ((size_t)b * NN + ri) * NN;
  #pragma unroll
  for (int i = 0; i < 4; ++i) {         // 2048 floats = 512 f32x4, 4/thread
    int off = (threadIdx.x + i * 128) * 4;
    *reinterpret_cast<f32x4*>(&srow[off]) =
        __builtin_nontemporal_load(reinterpret_cast<const f32x4*>(arow + off));
  }

  // fused new_X: 32 lanes x float4 = 128 floats
  if (threadIdx.x < 32) {
    float v = vals[row];
    const float4 xv = reinterpret_cast<const float4*>(
        X + ((size_t)b * NN + ri) * ND)[threadIdx.x];
    float4 o = make_float4(xv.x * v, xv.y * v, xv.z * v, xv.w * v);
    reinterpret_cast<float4*>(out_x + (size_t)row * ND)[threadIdx.x] = o;
  }
  __syncthreads();

  f32x4* orow = reinterpret_cast<f32x4*>(out_a + (size_t)row * MM);
  for (int c = threadIdx.x; c < MM / 4; c += 128) {
    const int4 j4 = *reinterpret_cast<const int4*>(scols + c * 4);
    f32x4 o;
    o.x = srow[j4.x];
    o.y = srow[j4.y];
    o.z = srow[j4.z];
    o.w = srow[j4.w];
    __builtin_nontemporal_store(o, orow + c);
  }
}

extern "C" void kernel_launch(void* const* d_in, const int* in_sizes, int n_in,
                              void* d_out, int out_size, void* d_ws, size_t ws_size,
                              hipStream_t stream) {
  const float* A    = (const float*)d_in[0];   // [32,2048,2048]
  const float* X    = (const float*)d_in[1];   // [32,2048,128]
  const float* w    = (const float*)d_in[2];   // [128]
  const float* bias = (const float*)d_in[3];   // [1]

  float* out0 = (float*)d_out;                          // new_A
  float* out1 = out0 + (size_t)NB * MM * MM;            // new_X
  float* out2 = out1 + (size_t)NB * MM * ND;            // idx (as f32)

  u64*   keys  = (u64*)d_ws;                 // [32][2048] u64
  float* score = (float*)(keys + NB * NN);   // [32][2048] f32
  int*   idxs  = (int*)(score + NB * NN);    // [32][1032] i32
  float* vals  = (float*)(idxs + NB * MM);   // [32][1032] f32

  hipLaunchKernelGGL(k_score, dim3(NB * NN / 256), dim3(256), 0, stream, X, w, bias, keys, score);
  hipLaunchKernelGGL(k_rank,  dim3(NB * 8),        dim3(256), 0, stream, keys, score, idxs, vals, out2);
  hipLaunchKernelGGL(k_newa,  dim3(NB * MM),       dim3(128), 0, stream, A, X, idxs, vals, out0, out1);
}